// Round 1
// baseline (129.197 us; speedup 1.0000x reference)
//
#include <hip/hip_runtime.h>

// field[i,j] = sum_n w[n]/(lx*ly) * ox(n,i) * oy(n,j)
// dims <= 3/G  =>  each rect spans at most 4 cells per axis => <=16 atomicAdds per rect.
__global__ void ChargeFieldModule_scatter(const float* __restrict__ boundary,
                                          const float2* __restrict__ xy,
                                          const float2* __restrict__ dims,
                                          const float* __restrict__ w,
                                          const int* __restrict__ grid_size,
                                          float* __restrict__ out,
                                          int n_rects) {
    int n = blockIdx.x * blockDim.x + threadIdx.x;
    if (n >= n_rects) return;

    float xmin = boundary[0], ymin = boundary[1];
    float xmax = boundary[2], ymax = boundary[3];
    int   G    = grid_size[0];
    float lx = (xmax - xmin) / (float)G;
    float ly = (ymax - ymin) / (float)G;

    float2 p = xy[n];
    float2 d = dims[n];
    float bx0 = p.x, by0 = p.y;
    float bx1 = bx0 + d.x, by1 = by0 + d.y;
    float cw = w[n] / (lx * ly);

    int i0 = (int)floorf((bx0 - xmin) / lx);
    int i1 = (int)floorf((bx1 - xmin) / lx);
    int j0 = (int)floorf((by0 - ymin) / ly);
    int j1 = (int)floorf((by1 - ymin) / ly);
    i0 = max(i0, 0); i1 = min(i1, G - 1);
    j0 = max(j0, 0); j1 = min(j1, G - 1);

    for (int i = i0; i <= i1; ++i) {
        float gx0 = xmin + (float)i * lx;
        float ox  = fminf(gx0 + lx, bx1) - fmaxf(gx0, bx0);
        ox = fmaxf(ox, 0.0f);
        if (ox <= 0.0f) continue;
        float cox = cw * ox;
        float* row = out + (size_t)i * (size_t)G;
        for (int j = j0; j <= j1; ++j) {
            float gy0 = ymin + (float)j * ly;
            float oy  = fminf(gy0 + ly, by1) - fmaxf(gy0, by0);
            oy = fmaxf(oy, 0.0f);
            if (oy > 0.0f) {
                atomicAdd(row + j, cox * oy);
            }
        }
    }
}

extern "C" void kernel_launch(void* const* d_in, const int* in_sizes, int n_in,
                              void* d_out, int out_size, void* d_ws, size_t ws_size,
                              hipStream_t stream) {
    const float*  boundary = (const float*)d_in[0];   // [[xmin,ymin],[xmax,ymax]] flat
    const float2* xy       = (const float2*)d_in[1];  // N x 2
    const float2* dims     = (const float2*)d_in[2];  // N x 2
    const float*  cweight  = (const float*)d_in[3];   // N
    const int*    gsize    = (const int*)d_in[4];     // scalar

    float* out = (float*)d_out;
    int n_rects = in_sizes[1] / 2;

    // Harness poisons d_out with 0xAA before every call — zero it on-stream.
    hipMemsetAsync(out, 0, (size_t)out_size * sizeof(float), stream);

    const int block = 256;
    const int grid  = (n_rects + block - 1) / block;
    ChargeFieldModule_scatter<<<grid, block, 0, stream>>>(
        boundary, xy, dims, cweight, gsize, out, n_rects);
}